// Round 4
// baseline (1130.938 us; speedup 1.0000x reference)
//
#include <hip/hip_runtime.h>
#include <hip/hip_fp16.h>
#include <hip/hip_cooperative_groups.h>

namespace cg = cooperative_groups;

#define NN 512
#define HROWS 256          // rows per block (half matrix)
#define WAVES 8            // 512 threads
#define RPW 32             // rows per wave
#define NITER 10

union H2U { uint32_t u; __half2 h; };

__device__ __forceinline__ float wave_reduce_sum(float v) {
    #pragma unroll
    for (int off = 32; off > 0; off >>= 1)
        v += __shfl_xor(v, off, 64);
    return v;   // all 64 lanes hold the sum
}

__device__ __forceinline__ void unpack8(const uint32_t q[4], float e[8]) {
    #pragma unroll
    for (int k = 0; k < 4; ++k) {
        H2U u; u.u = q[k];
        float2 f = __half22float2(u.h);
        e[2 * k]     = f.x;
        e[2 * k + 1] = f.y;
    }
}

// 2 blocks per matrix (block owns 256 rows, E=exp(S) register-resident as
// packed fp16: 128 VGPRs/thread at 512 thr/block). Fused sweep per Sinkhorn
// iteration: per row compute A_i = 1/dot(E_i, B_prev) (wave butterfly), then
// accumulate col partials c_j += E_ij*A_i. Column sums are completed by a
// pairwise partner exchange through global ws with release/acquire flags.
//
// __launch_bounds__(512, 1): the 2nd arg is min BLOCKS/CU (CUDA semantics,
// confirmed empirically R2/R3: (1024,4)->64 VGPR cap, (512,2)->128 cap).
// 1 block/CU = 2 waves/SIMD -> 256 VGPR cap -> Ereg[32][4] fits, no spill.
__global__ __launch_bounds__(512, 1)
void sinkhorn_pair(const float* __restrict__ Sg,
                   float* __restrict__ outg,
                   int* __restrict__ flags,
                   float* __restrict__ xdata,
                   int nmat) {
    cg::grid_group grid = cg::this_grid();

    const int blk  = blockIdx.x;
    const int mat  = blk % nmat;
    const int half = blk / nmat;           // pair partner: (1-half)*nmat+mat (same XCD under %8 dispatch)
    const size_t base = (size_t)mat * NN * NN + (size_t)half * HROWS * NN;
    const float* S = Sg + base;
    float* out = outg + base;

    __shared__ float Bv[NN];               // 1/col-sums (full 512)
    __shared__ float Av[HROWS];            // 1/row-sums (this block's rows)
    __shared__ float part[WAVES][NN];      // per-wave col partials (16 KB)

    const int tid  = threadIdx.x;
    const int lane = tid & 63;
    const int w    = tid >> 6;

    // ---- reset partner flags (ws is NOT re-poisoned between graph replays) ----
    if (tid < NITER)
        flags[(tid * 2 + half) * nmat + mat] = 0;
    __threadfence();
    grid.sync();

    // E fragment: rows w*32+rr (local), cols lane*8..+7, packed half2 x4
    uint32_t Ereg[RPW][4];
    float c[8] = {0.f, 0.f, 0.f, 0.f, 0.f, 0.f, 0.f, 0.f};

    // ---- sweep 0: E = exp(S); A = 1/rowsum (B=1); col partials with A ----
    #pragma unroll
    for (int rr = 0; rr < RPW; ++rr) {
        const int lr = w * RPW + rr;
        const float4* p = reinterpret_cast<const float4*>(S + (size_t)lr * NN + lane * 8);
        float4 x0 = p[0];
        float4 x1 = p[1];
        float e[8];
        e[0] = __expf(x0.x); e[1] = __expf(x0.y);
        e[2] = __expf(x0.z); e[3] = __expf(x0.w);
        e[4] = __expf(x1.x); e[5] = __expf(x1.y);
        e[6] = __expf(x1.z); e[7] = __expf(x1.w);
        #pragma unroll
        for (int q = 0; q < 4; ++q) {
            H2U u;
            u.h = __floats2half2_rn(e[2 * q], e[2 * q + 1]);
            Ereg[rr][q] = u.u;
        }
        float rs = ((e[0] + e[1]) + (e[2] + e[3])) + ((e[4] + e[5]) + (e[6] + e[7]));
        rs = wave_reduce_sum(rs);
        const float a = 1.0f / rs;
        if (lane == 0) Av[lr] = a;
        #pragma unroll
        for (int k = 0; k < 8; ++k) c[k] += e[k] * a;
    }

    // ---- per-iteration: complete col sums via partner exchange -> Bv ----
    for (int t = 0; t < NITER; ++t) {
        // (c[] holds this block's col partials for iteration t)
        *reinterpret_cast<float4*>(&part[w][lane * 8])     = make_float4(c[0], c[1], c[2], c[3]);
        *reinterpret_cast<float4*>(&part[w][lane * 8 + 4]) = make_float4(c[4], c[5], c[6], c[7]);
        __syncthreads();

        float mine = 0.f;
        #pragma unroll
        for (int k = 0; k < WAVES; ++k) mine += part[k][tid];

        const int myslot = (t * 2 + half) * nmat + mat;
        const int pfslot = (t * 2 + (1 - half)) * nmat + mat;
        xdata[(size_t)myslot * NN + tid] = mine;
        __threadfence();
        __syncthreads();
        if (tid == 0)
            __hip_atomic_store(&flags[myslot], 1, __ATOMIC_RELEASE, __HIP_MEMORY_SCOPE_AGENT);
        while (__hip_atomic_load(&flags[pfslot], __ATOMIC_ACQUIRE, __HIP_MEMORY_SCOPE_AGENT) == 0) {}
        const float theirs = xdata[(size_t)pfslot * NN + tid];
        Bv[tid] = 1.0f / (mine + theirs);   // commutative -> identical in both blocks
        __syncthreads();

        if (t == NITER - 1) break;          // B^(9) done; A^(9) already in Av

        // ---- fused sweep t+1: A_i = 1/dot(E_i, B); c_j += E_ij * A_i ----
        float b[8];
        #pragma unroll
        for (int k = 0; k < 8; ++k) b[k] = Bv[lane * 8 + k];
        #pragma unroll
        for (int k = 0; k < 8; ++k) c[k] = 0.f;
        #pragma unroll
        for (int rr = 0; rr < RPW; ++rr) {
            float e[8];
            unpack8(Ereg[rr], e);
            float d = 0.f;
            #pragma unroll
            for (int k = 0; k < 8; ++k) d += e[k] * b[k];
            d = wave_reduce_sum(d);
            const float a = 1.0f / d;
            if (lane == 0) Av[w * RPW + rr] = a;
            #pragma unroll
            for (int k = 0; k < 8; ++k) c[k] += e[k] * a;
        }
        __syncthreads();
    }

    // ---- final: out_ij = E_ij * A_i * B_j ----
    {
        float b[8];
        #pragma unroll
        for (int k = 0; k < 8; ++k) b[k] = Bv[lane * 8 + k];
        #pragma unroll
        for (int rr = 0; rr < RPW; ++rr) {
            const int lr = w * RPW + rr;
            const float a = Av[lr];
            float e[8];
            unpack8(Ereg[rr], e);
            float* op = out + (size_t)lr * NN + lane * 8;
            reinterpret_cast<float4*>(op)[0] =
                make_float4(e[0] * a * b[0], e[1] * a * b[1], e[2] * a * b[2], e[3] * a * b[3]);
            reinterpret_cast<float4*>(op)[1] =
                make_float4(e[4] * a * b[4], e[5] * a * b[5], e[6] * a * b[6], e[7] * a * b[7]);
        }
    }
}

extern "C" void kernel_launch(void* const* d_in, const int* in_sizes, int n_in,
                              void* d_out, int out_size, void* d_ws, size_t ws_size,
                              hipStream_t stream) {
    const float* S = reinterpret_cast<const float*>(d_in[0]);
    float* out = reinterpret_cast<float*>(d_out);
    const int nmat = in_sizes[0] / (NN * NN);   // 128 for (8,16,512,512)

    // ws layout: [flags: NITER*2*nmat ints][pad to 64KB][xdata: NITER*2*nmat*NN floats]
    int* flags = reinterpret_cast<int*>(d_ws);
    float* xdata = reinterpret_cast<float*>(reinterpret_cast<char*>(d_ws) + (64 << 10));

    dim3 grid(2 * nmat);
    dim3 block(512);
    void* args[] = { (void*)&S, (void*)&out, (void*)&flags, (void*)&xdata, (void*)&nmat };
    (void)hipLaunchCooperativeKernel(reinterpret_cast<const void*>(&sinkhorn_pair),
                                     grid, block, args, 0, stream);
}

// Round 5
// 1128.933 us; speedup vs baseline: 1.0018x; 1.0018x over previous
//
#include <hip/hip_runtime.h>
#include <hip/hip_fp16.h>
#include <hip/hip_cooperative_groups.h>

namespace cg = cooperative_groups;

#define NN 512
#define HROWS 256          // rows per block (half matrix)
#define WAVES 8            // 512 threads
#define RPW 32             // rows per wave
#define NITER 10

union H2U { uint32_t u; __half2 h; };

__device__ __forceinline__ float wave_reduce_sum(float v) {
    #pragma unroll
    for (int off = 32; off > 0; off >>= 1)
        v += __shfl_xor(v, off, 64);
    return v;   // all 64 lanes hold the sum
}

__device__ __forceinline__ void unpack8(const uint32_t q[4], float e[8]) {
    #pragma unroll
    for (int k = 0; k < 4; ++k) {
        H2U u; u.u = q[k];
        float2 f = __half22float2(u.h);
        e[2 * k]     = f.x;
        e[2 * k + 1] = f.y;
    }
}

// 2 blocks per matrix (block owns 256 rows, E=exp(S) register-resident as
// packed fp16: 128 VGPRs/thread at 512 thr/block). Fused sweep per Sinkhorn
// iteration: per row compute A_i = 1/dot(E_i, B_prev) (wave butterfly), then
// accumulate col partials c_j += E_ij*A_i. Column sums are completed by a
// pairwise partner exchange through global ws with release/acquire flags.
//
// amdgpu_waves_per_eu(2,2): R2-R4 showed launch_bounds alone leaves the
// scheduler's occupancy heuristic targeting 4 waves/EU (128-VGPR budget ->
// Ereg spills to scratch; VGPR_Count=128, ~140MB extra FETCH+WRITE).
// Cooperative launch gives exactly 1 block/CU = 2 waves/EU, so pin the
// compiler's occupancy target to 2 (VGPR cap 256, Ereg+working ~190 fits).
__global__ __launch_bounds__(512)
__attribute__((amdgpu_waves_per_eu(2, 2)))
void sinkhorn_pair(const float* __restrict__ Sg,
                   float* __restrict__ outg,
                   int* __restrict__ flags,
                   float* __restrict__ xdata,
                   int nmat) {
    cg::grid_group grid = cg::this_grid();

    const int blk  = blockIdx.x;
    const int mat  = blk % nmat;
    const int half = blk / nmat;           // pair partner: (1-half)*nmat+mat (same XCD under %8 dispatch)
    const size_t base = (size_t)mat * NN * NN + (size_t)half * HROWS * NN;
    const float* S = Sg + base;
    float* out = outg + base;

    __shared__ float Bv[NN];               // 1/col-sums (full 512)
    __shared__ float Av[HROWS];            // 1/row-sums (this block's rows)
    __shared__ float part[WAVES][NN];      // per-wave col partials (16 KB)

    const int tid  = threadIdx.x;
    const int lane = tid & 63;
    const int w    = tid >> 6;

    // ---- reset partner flags (ws is NOT re-poisoned between graph replays) ----
    if (tid < NITER)
        flags[(tid * 2 + half) * nmat + mat] = 0;
    __threadfence();
    grid.sync();

    // E fragment: rows w*32+rr (local), cols lane*8..+7, packed half2 x4
    uint32_t Ereg[RPW][4];
    float c[8] = {0.f, 0.f, 0.f, 0.f, 0.f, 0.f, 0.f, 0.f};

    // ---- sweep 0: E = exp(S); A = 1/rowsum (B=1); col partials with A ----
    #pragma unroll
    for (int rr = 0; rr < RPW; ++rr) {
        const int lr = w * RPW + rr;
        const float4* p = reinterpret_cast<const float4*>(S + (size_t)lr * NN + lane * 8);
        float4 x0 = p[0];
        float4 x1 = p[1];
        float e[8];
        e[0] = __expf(x0.x); e[1] = __expf(x0.y);
        e[2] = __expf(x0.z); e[3] = __expf(x0.w);
        e[4] = __expf(x1.x); e[5] = __expf(x1.y);
        e[6] = __expf(x1.z); e[7] = __expf(x1.w);
        #pragma unroll
        for (int q = 0; q < 4; ++q) {
            H2U u;
            u.h = __floats2half2_rn(e[2 * q], e[2 * q + 1]);
            Ereg[rr][q] = u.u;
        }
        float rs = ((e[0] + e[1]) + (e[2] + e[3])) + ((e[4] + e[5]) + (e[6] + e[7]));
        rs = wave_reduce_sum(rs);
        const float a = 1.0f / rs;
        if (lane == 0) Av[lr] = a;
        #pragma unroll
        for (int k = 0; k < 8; ++k) c[k] += e[k] * a;
    }

    // ---- per-iteration: complete col sums via partner exchange -> Bv ----
    for (int t = 0; t < NITER; ++t) {
        // (c[] holds this block's col partials for iteration t)
        *reinterpret_cast<float4*>(&part[w][lane * 8])     = make_float4(c[0], c[1], c[2], c[3]);
        *reinterpret_cast<float4*>(&part[w][lane * 8 + 4]) = make_float4(c[4], c[5], c[6], c[7]);
        __syncthreads();

        float mine = 0.f;
        #pragma unroll
        for (int k = 0; k < WAVES; ++k) mine += part[k][tid];

        const int myslot = (t * 2 + half) * nmat + mat;
        const int pfslot = (t * 2 + (1 - half)) * nmat + mat;
        xdata[(size_t)myslot * NN + tid] = mine;
        __threadfence();
        __syncthreads();
        if (tid == 0)
            __hip_atomic_store(&flags[myslot], 1, __ATOMIC_RELEASE, __HIP_MEMORY_SCOPE_AGENT);
        while (__hip_atomic_load(&flags[pfslot], __ATOMIC_ACQUIRE, __HIP_MEMORY_SCOPE_AGENT) == 0) {}
        const float theirs = xdata[(size_t)pfslot * NN + tid];
        Bv[tid] = 1.0f / (mine + theirs);   // commutative -> identical in both blocks
        __syncthreads();

        if (t == NITER - 1) break;          // B^(9) done; A^(9) already in Av

        // ---- fused sweep t+1: A_i = 1/dot(E_i, B); c_j += E_ij * A_i ----
        float b[8];
        #pragma unroll
        for (int k = 0; k < 8; ++k) b[k] = Bv[lane * 8 + k];
        #pragma unroll
        for (int k = 0; k < 8; ++k) c[k] = 0.f;
        #pragma unroll
        for (int rr = 0; rr < RPW; ++rr) {
            float e[8];
            unpack8(Ereg[rr], e);
            float d = 0.f;
            #pragma unroll
            for (int k = 0; k < 8; ++k) d += e[k] * b[k];
            d = wave_reduce_sum(d);
            const float a = 1.0f / d;
            if (lane == 0) Av[w * RPW + rr] = a;
            #pragma unroll
            for (int k = 0; k < 8; ++k) c[k] += e[k] * a;
        }
        __syncthreads();
    }

    // ---- final: out_ij = E_ij * A_i * B_j ----
    {
        float b[8];
        #pragma unroll
        for (int k = 0; k < 8; ++k) b[k] = Bv[lane * 8 + k];
        #pragma unroll
        for (int rr = 0; rr < RPW; ++rr) {
            const int lr = w * RPW + rr;
            const float a = Av[lr];
            float e[8];
            unpack8(Ereg[rr], e);
            float* op = out + (size_t)lr * NN + lane * 8;
            reinterpret_cast<float4*>(op)[0] =
                make_float4(e[0] * a * b[0], e[1] * a * b[1], e[2] * a * b[2], e[3] * a * b[3]);
            reinterpret_cast<float4*>(op)[1] =
                make_float4(e[4] * a * b[4], e[5] * a * b[5], e[6] * a * b[6], e[7] * a * b[7]);
        }
    }
}

extern "C" void kernel_launch(void* const* d_in, const int* in_sizes, int n_in,
                              void* d_out, int out_size, void* d_ws, size_t ws_size,
                              hipStream_t stream) {
    const float* S = reinterpret_cast<const float*>(d_in[0]);
    float* out = reinterpret_cast<float*>(d_out);
    const int nmat = in_sizes[0] / (NN * NN);   // 128 for (8,16,512,512)

    // ws layout: [flags: NITER*2*nmat ints][pad to 64KB][xdata: NITER*2*nmat*NN floats]
    int* flags = reinterpret_cast<int*>(d_ws);
    float* xdata = reinterpret_cast<float*>(reinterpret_cast<char*>(d_ws) + (64 << 10));

    dim3 grid(2 * nmat);
    dim3 block(512);
    void* args[] = { (void*)&S, (void*)&out, (void*)&flags, (void*)&xdata, (void*)&nmat };
    (void)hipLaunchCooperativeKernel(reinterpret_cast<const void*>(&sinkhorn_pair),
                                     grid, block, args, 0, stream);
}